// Round 6
// baseline (143.821 us; speedup 1.0000x reference)
//
#include <hip/hip_runtime.h>
#include <hip/hip_bf16.h>
#include <math.h>

#define Bn 8
#define Tn 2048
#define Cn 1024
#define Hn 64

typedef __attribute__((ext_vector_type(8))) short short8;
typedef __attribute__((ext_vector_type(4))) float floatx4;

#define ATTN_SCALE 0.18033688011112042f   // log2(e) / sqrt(64)

__device__ inline unsigned short f2bf(float f) {
    union { float f; unsigned int u; } x; x.f = f;
    unsigned int r = x.u + 0x7fffu + ((x.u >> 16) & 1u);
    return (unsigned short)(r >> 16);
}

__device__ inline uint2 pack4bf(float4 v) {
    __hip_bfloat162 lo = __float22bfloat162_rn(make_float2(v.x, v.y));
    __hip_bfloat162 hi = __float22bfloat162_rn(make_float2(v.z, v.w));
    uint2 r;
    r.x = *reinterpret_cast<unsigned int*>(&lo);
    r.y = *reinterpret_cast<unsigned int*>(&hi);
    return r;
}

__device__ inline float rsum16(float v) {
    v += __shfl_xor(v, 1);
    v += __shfl_xor(v, 2);
    v += __shfl_xor(v, 4);
    v += __shfl_xor(v, 8);
    return v;
}

// ---------------------------------------------------------------------------
// Kernel 0: W -> bf16 in MFMA B-FRAGMENT ORDER.  (unchanged)
// Wfrag[(c*32 + ks)*64 + lane][8]:  lane = ln + 16*qd holds
//   W_mat[k = ks*32 + qd*8 + j][col = nc*16 + ln],  c = mat*4 + nc.
// ---------------------------------------------------------------------------
__global__ __launch_bounds__(256) void prep_w(
    const float* __restrict__ Wq, const float* __restrict__ Wk,
    const float* __restrict__ Wv, unsigned short* __restrict__ Wfrag)
{
    const int gid = blockIdx.x * 256 + threadIdx.x;   // 0..24575
    const int c    = gid >> 11;
    const int rem  = gid & 2047;
    const int ks   = rem >> 6;
    const int lane = rem & 63;
    const int ln = lane & 15, qd = lane >> 4;
    const int mat = c >> 2, nc = c & 3;
    const float* W = (mat == 0) ? Wq : (mat == 1) ? Wk : Wv;
    const float sc = (mat == 0) ? ATTN_SCALE : 1.0f;
    const int col = nc * 16 + ln;
    unsigned short o[8];
    #pragma unroll
    for (int j = 0; j < 8; ++j)
        o[j] = f2bf(W[(size_t)(ks * 32 + qd * 8 + j) * Hn + col] * sc);
    *reinterpret_cast<short8*>(Wfrag + (size_t)gid * 8) = *reinterpret_cast<short8*>(o);
}

// ---------------------------------------------------------------------------
// Kernel 1: fused QKV projection — BARRIER-FREE SPLIT-K.
// 1024 blocks x 4 waves, 16 rows/block.  wave = (wk = K-half of 512,
// wn = 6-of-12 output chunks).  Main loop: x streamed global->reg->
// cvt_pk_bf16->MFMA (no LDS, no barriers); B-frags lane-contiguous from
// Wfrag (L2-hot).  One barrier: wk=1 waves write fp32 partials to LDS,
// wk=0 waves add + scatter epilogue (epilogue code verified rounds 4-5).
// ---------------------------------------------------------------------------
__global__ __launch_bounds__(256, 4) void proj_mfma(
    const float* __restrict__ x, const unsigned short* __restrict__ Wfrag,
    unsigned short* __restrict__ qbf, unsigned short* __restrict__ kfrag,
    unsigned short* __restrict__ vfrag)
{
    __shared__ float part[2][6][16][17];        // 13.1 KB

    const int ln   = threadIdx.x & 15;
    const int quad = (threadIdx.x >> 4) & 3;
    const int w    = threadIdx.x >> 6;
    const int lane = threadIdx.x & 63;
    const int wk = w & 1, wn = w >> 1;
    const int row0 = blockIdx.x * 16;

    const float* xr = x + (size_t)(row0 + ln) * Cn + wk * 512 + quad * 8;

    floatx4 acc[6];
    #pragma unroll
    for (int i = 0; i < 6; ++i) acc[i] = (floatx4){0.f, 0.f, 0.f, 0.f};

    #pragma unroll 2
    for (int ks = 0; ks < 16; ++ks) {
        const float4 xa = *reinterpret_cast<const float4*>(xr + ks * 32);
        const float4 xb = *reinterpret_cast<const float4*>(xr + ks * 32 + 4);
        union { uint2 u2[2]; short8 s8; } a;
        a.u2[0] = pack4bf(xa);
        a.u2[1] = pack4bf(xb);
        const int kstep = wk * 16 + ks;
        #pragma unroll
        for (int i = 0; i < 6; ++i) {
            const int cc = wn * 6 + i;
            const short8 b = *reinterpret_cast<const short8*>(
                Wfrag + ((size_t)(cc * 32 + kstep) * 64 + lane) * 8);
            acc[i] = __builtin_amdgcn_mfma_f32_16x16x32_bf16(a.s8, b, acc[i], 0, 0, 0);
        }
    }

    if (wk == 1) {
        #pragma unroll
        for (int i = 0; i < 6; ++i)
            #pragma unroll
            for (int r = 0; r < 4; ++r)
                part[wn][i][quad * 4 + r][ln] = acc[i][r];
    }
    __syncthreads();
    if (wk == 1) return;

    // wk == 0: add partner partial, then scatter epilogue.
    #pragma unroll
    for (int i = 0; i < 6; ++i)
        #pragma unroll
        for (int r = 0; r < 4; ++r)
            acc[i][r] += part[wn][i][quad * 4 + r][ln];

    // epilogue: C layout col = ln, row = quad*4 + r   (verified rounds 4-5)
    const int t0   = row0 + quad * 4;
    const int b    = t0 >> 11;
    const int tloc = t0 & 2047;
    #pragma unroll
    for (int i = 0; i < 6; ++i) {
        const int idx = wn * 6 + i;
        const int mat = idx >> 2, ch = idx & 3;
        if (mat == 0) {
            #pragma unroll
            for (int r = 0; r < 4; ++r)
                qbf[(size_t)(t0 + r) * Hn + ch * 16 + ln] = f2bf(acc[i][r]);
        } else if (mat == 1) {
            const int kc = tloc >> 4;
            const int ks = ch >> 1;
            const int lq = (ch & 1) * 2 + (ln >> 3);
            #pragma unroll
            for (int r = 0; r < 4; ++r) {
                const int lanep = (quad * 4 + r) + 16 * lq;
                kfrag[(((size_t)(b * 128 + kc) * 2 + ks) * 64 + lanep) * 8 + (ln & 7)]
                    = f2bf(acc[i][r]);
            }
        } else {
            const int kb32 = tloc >> 5;
            const int off  = t0 & 31;
            const int qd   = off >> 3;
            const int j0   = off & 7;
            const int lanep = ln + 16 * qd;
            ushort4 pk;
            pk.x = f2bf(acc[i][0]); pk.y = f2bf(acc[i][1]);
            pk.z = f2bf(acc[i][2]); pk.w = f2bf(acc[i][3]);
            *reinterpret_cast<ushort4*>(
                vfrag + (((size_t)(b * 64 + kb32) * 4 + ch) * 64 + lanep) * 8 + j0) = pk;
        }
    }
}

// ---------------------------------------------------------------------------
// Kernel 2: causal flash attention.  (byte-identical to round 5 — frozen)
// ---------------------------------------------------------------------------
__global__ __launch_bounds__(256, 4) void attn_mfma(
    const unsigned short* __restrict__ qbf, const unsigned short* __restrict__ kfrag,
    const unsigned short* __restrict__ vt, float* __restrict__ out)
{
    __shared__ unsigned short p_lds[4][16 * 40];     // 5.1 KB
    __shared__ float o_lds[4][16][68];               // 17.4 KB
    __shared__ float l_lds[4][16];

    const int j  = blockIdx.x;
    const int b  = j & 7;
    const int ti = 127 - (j >> 3);                   // heavy tiles first
    const int q0 = ti * 16;

    const int ln   = threadIdx.x & 15;
    const int quad = (threadIdx.x >> 4) & 3;
    const int w    = threadIdx.x >> 6;
    const int lane = threadIdx.x & 63;

    const unsigned short* qb = qbf + (size_t)b * Tn * Hn;
    const unsigned short* Kb = kfrag + (size_t)b * 131072;
    const unsigned short* Vb = vt + (size_t)b * 131072;

    const short8 aq0 = *reinterpret_cast<const short8*>(qb + (size_t)(q0 + ln) * Hn + quad * 8);
    const short8 aq1 = *reinterpret_cast<const short8*>(qb + (size_t)(q0 + ln) * Hn + 32 + quad * 8);

    floatx4 O[4];
    #pragma unroll
    for (int c = 0; c < 4; ++c) O[c] = (floatx4){0.f, 0.f, 0.f, 0.f};
    float lp[4] = {0.f, 0.f, 0.f, 0.f};

    const int ntiles = (q0 + 47) >> 5;
    const int per    = (ntiles + 3) >> 2;
    const int beg    = w * per;
    const int end    = min(beg + per, ntiles);
    unsigned short* pP = p_lds[w];

    short8 kf[4];
    if (beg < end) {
        #pragma unroll
        for (int u = 0; u < 4; ++u)
            kf[u] = *reinterpret_cast<const short8*>(Kb + ((size_t)(beg * 4 + u)) * 512 + lane * 8);
    }

    for (int t = beg; t < end; ++t) {
        const int tn = (t + 1 < end) ? (t + 1) : t;
        short8 kn[4], vf[4];
        #pragma unroll
        for (int u = 0; u < 4; ++u) {
            kn[u] = *reinterpret_cast<const short8*>(Kb + ((size_t)(tn * 4 + u)) * 512 + lane * 8);
            vf[u] = *reinterpret_cast<const short8*>(Vb + ((size_t)(t * 4 + u)) * 512 + lane * 8);
        }

        const floatx4 z = (floatx4){0.f, 0.f, 0.f, 0.f};
        floatx4 S[2];
        #pragma unroll
        for (int s = 0; s < 2; ++s) {
            S[s] = __builtin_amdgcn_mfma_f32_16x16x32_bf16(aq0, kf[s * 2], z, 0, 0, 0);
            S[s] = __builtin_amdgcn_mfma_f32_16x16x32_bf16(aq1, kf[s * 2 + 1], S[s], 0, 0, 0);
        }

        const bool diag = (t == ntiles - 1);
        #pragma unroll
        for (int s = 0; s < 2; ++s) {
            #pragma unroll
            for (int r = 0; r < 4; ++r) {
                float sv = S[s][r];
                if (diag && (t * 32 + s * 16 + ln > q0 + quad * 4 + r)) sv = -1e30f;
                const unsigned int pu = __float_as_uint(exp2f(sv));
                lp[r] += __uint_as_float(pu & 0xffff0000u);
                pP[(quad * 4 + r) * 40 + s * 16 + ln] = (unsigned short)(pu >> 16);
            }
        }
        __asm__ volatile("s_waitcnt lgkmcnt(0)" ::: "memory");
        const short8 pa = *reinterpret_cast<const short8*>(pP + ln * 40 + quad * 8);
        #pragma unroll
        for (int c = 0; c < 4; ++c)
            O[c] = __builtin_amdgcn_mfma_f32_16x16x32_bf16(pa, vf[c], O[c], 0, 0, 0);
        #pragma unroll
        for (int u = 0; u < 4; ++u) kf[u] = kn[u];
    }

    #pragma unroll
    for (int c = 0; c < 4; ++c)
        #pragma unroll
        for (int r = 0; r < 4; ++r)
            o_lds[w][quad * 4 + r][c * 16 + ln] = O[c][r];
    #pragma unroll
    for (int r = 0; r < 4; ++r) {
        const float ls = rsum16(lp[r]);
        if (ln == 0) l_lds[w][quad * 4 + r] = ls;
    }
    __syncthreads();

    const int qq = threadIdx.x >> 4;
    const int dg = threadIdx.x & 15;
    const float ltot = l_lds[0][qq] + l_lds[1][qq] + l_lds[2][qq] + l_lds[3][qq];
    const float inv = 1.0f / ltot;
    const float4 a0 = *reinterpret_cast<float4*>(&o_lds[0][qq][dg * 4]);
    const float4 a1 = *reinterpret_cast<float4*>(&o_lds[1][qq][dg * 4]);
    const float4 a2 = *reinterpret_cast<float4*>(&o_lds[2][qq][dg * 4]);
    const float4 a3 = *reinterpret_cast<float4*>(&o_lds[3][qq][dg * 4]);
    float4 r;
    r.x = (a0.x + a1.x + a2.x + a3.x) * inv;
    r.y = (a0.y + a1.y + a2.y + a3.y) * inv;
    r.z = (a0.z + a1.z + a2.z + a3.z) * inv;
    r.w = (a0.w + a1.w + a2.w + a3.w) * inv;
    *reinterpret_cast<float4*>(out + ((size_t)b * Tn + q0 + qq) * Hn + dg * 4) = r;
}

// ---------------------------------------------------------------------------
extern "C" void kernel_launch(void* const* d_in, const int* in_sizes, int n_in,
                              void* d_out, int out_size, void* d_ws, size_t ws_size,
                              hipStream_t stream) {
    (void)in_sizes; (void)n_in; (void)out_size; (void)ws_size;
    const float* x  = (const float*)d_in[0];
    const float* Wq = (const float*)d_in[1];
    const float* Wk = (const float*)d_in[2];
    const float* Wv = (const float*)d_in[3];
    float* out = (float*)d_out;

    unsigned short* Wfrag = (unsigned short*)d_ws;            // 196608
    unsigned short* qbf   = Wfrag + (size_t)196608;           // 1048576
    unsigned short* kfr   = qbf + (size_t)Bn * Tn * Hn;       // 1048576
    unsigned short* vfr   = kfr + (size_t)Bn * 131072;        // 1048576

    prep_w<<<96, 256, 0, stream>>>(Wq, Wk, Wv, Wfrag);
    proj_mfma<<<(Bn * Tn) / 16, 256, 0, stream>>>(x, Wfrag, qbf, kfr, vfr);
    attn_mfma<<<Bn * (Tn / 16), 256, 0, stream>>>(qbf, kfr, vfr, out);
}

// Round 7
// 125.025 us; speedup vs baseline: 1.1503x; 1.1503x over previous
//
#include <hip/hip_runtime.h>
#include <hip/hip_bf16.h>
#include <math.h>

#define Bn 8
#define Tn 2048
#define Cn 1024
#define Hn 64

typedef __attribute__((ext_vector_type(8))) short short8;
typedef __attribute__((ext_vector_type(4))) float floatx4;

#define ATTN_SCALE 0.18033688011112042f   // log2(e) / sqrt(64)

__device__ inline unsigned short f2bf(float f) {
    union { float f; unsigned int u; } x; x.f = f;
    unsigned int r = x.u + 0x7fffu + ((x.u >> 16) & 1u);
    return (unsigned short)(r >> 16);
}

__device__ inline uint2 pack4bf(float4 v) {
    __hip_bfloat162 lo = __float22bfloat162_rn(make_float2(v.x, v.y));
    __hip_bfloat162 hi = __float22bfloat162_rn(make_float2(v.z, v.w));
    uint2 r;
    r.x = *reinterpret_cast<unsigned int*>(&lo);
    r.y = *reinterpret_cast<unsigned int*>(&hi);
    return r;
}

__device__ inline float rsum16(float v) {
    v += __shfl_xor(v, 1);
    v += __shfl_xor(v, 2);
    v += __shfl_xor(v, 4);
    v += __shfl_xor(v, 8);
    return v;
}

// ---------------------------------------------------------------------------
// Kernel 0: W -> bf16 in MFMA B-FRAGMENT ORDER.  (unchanged)
// ---------------------------------------------------------------------------
__global__ __launch_bounds__(256) void prep_w(
    const float* __restrict__ Wq, const float* __restrict__ Wk,
    const float* __restrict__ Wv, unsigned short* __restrict__ Wfrag)
{
    const int gid = blockIdx.x * 256 + threadIdx.x;   // 0..24575
    const int c    = gid >> 11;
    const int rem  = gid & 2047;
    const int ks   = rem >> 6;
    const int lane = rem & 63;
    const int ln = lane & 15, qd = lane >> 4;
    const int mat = c >> 2, nc = c & 3;
    const float* W = (mat == 0) ? Wq : (mat == 1) ? Wk : Wv;
    const float sc = (mat == 0) ? ATTN_SCALE : 1.0f;
    const int col = nc * 16 + ln;
    unsigned short o[8];
    #pragma unroll
    for (int j = 0; j < 8; ++j)
        o[j] = f2bf(W[(size_t)(ks * 32 + qd * 8 + j) * Hn + col] * sc);
    *reinterpret_cast<short8*>(Wfrag + (size_t)gid * 8) = *reinterpret_cast<short8*>(o);
}

// ---------------------------------------------------------------------------
// Kernel 1: fused QKV projection — SINGLE-STAGE LDS, BARRIER-FREE COMPUTE.
// 1024 blocks x 4 waves, 16 rows/block, 4 blocks/CU.
// Phase 1: whole 16x1024 x-tile -> LDS in A-FRAGMENT order (bf16, 32 KB),
//   fully-coalesced float4 loads, 16 in flight per thread (deep MLP).
// ONE barrier.
// Phase 2: per wave, 32 k-steps x 3 n-chunks = 96 MFMAs, zero barriers;
//   A-frag = conflict-free ds_read_b128 (lane-contiguous); B-frag = Wfrag
//   (L2-hot) lane-contiguous 16B loads.
// Frag layout: xs short-offset = s*512 + (q*16 + row)*8 + j  for element
//   x[row][k], s = k>>5, q = (k>>3)&3, j = k&7.  Reader: lane (ln+16q)
//   reads 16B at s*1024 + lane*16 bytes -> conflict-free.
// ---------------------------------------------------------------------------
__global__ __launch_bounds__(256, 4) void proj_mfma(
    const float* __restrict__ x, const unsigned short* __restrict__ Wfrag,
    unsigned short* __restrict__ qbf, unsigned short* __restrict__ kfrag,
    unsigned short* __restrict__ vfrag)
{
    __shared__ unsigned short xs[32 * 512];     // 32 KB

    const int ln   = threadIdx.x & 15;
    const int quad = (threadIdx.x >> 4) & 3;
    const int w    = threadIdx.x >> 6;
    const int lane = threadIdx.x & 63;
    const int row0 = blockIdx.x * 16;

    // ---- phase 1: stage x tile ----
    const int srow = threadIdx.x >> 4;          // 0..15
    const int sf   = threadIdx.x & 15;          // f4 slot base
    const float4* xrow4 = reinterpret_cast<const float4*>(x + (size_t)(row0 + srow) * Cn);

    float4 ld[16];
    #pragma unroll
    for (int it = 0; it < 16; ++it)
        ld[it] = xrow4[sf + 16 * it];
    #pragma unroll
    for (int it = 0; it < 16; ++it) {
        const int f4g = sf + 16 * it;
        const int s = f4g >> 3;
        const int q = (f4g >> 1) & 3;
        const int j = (f4g & 1) * 4;
        *reinterpret_cast<uint2*>(&xs[s * 512 + (q * 16 + srow) * 8 + j]) = pack4bf(ld[it]);
    }
    __syncthreads();

    // ---- phase 2: barrier-free MFMA stream ----
    floatx4 acc[3];
    #pragma unroll
    for (int i = 0; i < 3; ++i) acc[i] = (floatx4){0.f, 0.f, 0.f, 0.f};

    #pragma unroll 4
    for (int s = 0; s < 32; ++s) {
        const short8 a = *reinterpret_cast<const short8*>(&xs[s * 512 + lane * 8]);
        #pragma unroll
        for (int i = 0; i < 3; ++i) {
            const int cc = w * 3 + i;
            const short8 b = *reinterpret_cast<const short8*>(
                Wfrag + ((size_t)(cc * 32 + s) * 64 + lane) * 8);
            acc[i] = __builtin_amdgcn_mfma_f32_16x16x32_bf16(a, b, acc[i], 0, 0, 0);
        }
    }

    // epilogue: C layout col = ln, row = quad*4 + r   (round-4-verified, idx = w*3+i)
    const int t0   = row0 + quad * 4;
    const int b    = t0 >> 11;
    const int tloc = t0 & 2047;
    #pragma unroll
    for (int i = 0; i < 3; ++i) {
        const int idx = w * 3 + i;
        const int mat = idx >> 2, ch = idx & 3;
        if (mat == 0) {
            #pragma unroll
            for (int r = 0; r < 4; ++r)
                qbf[(size_t)(t0 + r) * Hn + ch * 16 + ln] = f2bf(acc[i][r]);
        } else if (mat == 1) {
            const int kc = tloc >> 4;
            const int ks = ch >> 1;
            const int lq = (ch & 1) * 2 + (ln >> 3);
            #pragma unroll
            for (int r = 0; r < 4; ++r) {
                const int lanep = (quad * 4 + r) + 16 * lq;
                kfrag[(((size_t)(b * 128 + kc) * 2 + ks) * 64 + lanep) * 8 + (ln & 7)]
                    = f2bf(acc[i][r]);
            }
        } else {
            const int kb32 = tloc >> 5;
            const int off  = t0 & 31;
            const int qd   = off >> 3;
            const int j0   = off & 7;
            const int lanep = ln + 16 * qd;
            ushort4 pk;
            pk.x = f2bf(acc[i][0]); pk.y = f2bf(acc[i][1]);
            pk.z = f2bf(acc[i][2]); pk.w = f2bf(acc[i][3]);
            *reinterpret_cast<ushort4*>(
                vfrag + (((size_t)(b * 64 + kb32) * 4 + ch) * 64 + lanep) * 8 + j0) = pk;
        }
    }
}

// ---------------------------------------------------------------------------
// Kernel 2: causal flash attention.  (byte-identical to rounds 5/6 — frozen)
// ---------------------------------------------------------------------------
__global__ __launch_bounds__(256, 4) void attn_mfma(
    const unsigned short* __restrict__ qbf, const unsigned short* __restrict__ kfrag,
    const unsigned short* __restrict__ vt, float* __restrict__ out)
{
    __shared__ unsigned short p_lds[4][16 * 40];     // 5.1 KB
    __shared__ float o_lds[4][16][68];               // 17.4 KB
    __shared__ float l_lds[4][16];

    const int j  = blockIdx.x;
    const int b  = j & 7;
    const int ti = 127 - (j >> 3);                   // heavy tiles first
    const int q0 = ti * 16;

    const int ln   = threadIdx.x & 15;
    const int quad = (threadIdx.x >> 4) & 3;
    const int w    = threadIdx.x >> 6;
    const int lane = threadIdx.x & 63;

    const unsigned short* qb = qbf + (size_t)b * Tn * Hn;
    const unsigned short* Kb = kfrag + (size_t)b * 131072;
    const unsigned short* Vb = vt + (size_t)b * 131072;

    const short8 aq0 = *reinterpret_cast<const short8*>(qb + (size_t)(q0 + ln) * Hn + quad * 8);
    const short8 aq1 = *reinterpret_cast<const short8*>(qb + (size_t)(q0 + ln) * Hn + 32 + quad * 8);

    floatx4 O[4];
    #pragma unroll
    for (int c = 0; c < 4; ++c) O[c] = (floatx4){0.f, 0.f, 0.f, 0.f};
    float lp[4] = {0.f, 0.f, 0.f, 0.f};

    const int ntiles = (q0 + 47) >> 5;
    const int per    = (ntiles + 3) >> 2;
    const int beg    = w * per;
    const int end    = min(beg + per, ntiles);
    unsigned short* pP = p_lds[w];

    short8 kf[4];
    if (beg < end) {
        #pragma unroll
        for (int u = 0; u < 4; ++u)
            kf[u] = *reinterpret_cast<const short8*>(Kb + ((size_t)(beg * 4 + u)) * 512 + lane * 8);
    }

    for (int t = beg; t < end; ++t) {
        const int tn = (t + 1 < end) ? (t + 1) : t;
        short8 kn[4], vf[4];
        #pragma unroll
        for (int u = 0; u < 4; ++u) {
            kn[u] = *reinterpret_cast<const short8*>(Kb + ((size_t)(tn * 4 + u)) * 512 + lane * 8);
            vf[u] = *reinterpret_cast<const short8*>(Vb + ((size_t)(t * 4 + u)) * 512 + lane * 8);
        }

        const floatx4 z = (floatx4){0.f, 0.f, 0.f, 0.f};
        floatx4 S[2];
        #pragma unroll
        for (int s = 0; s < 2; ++s) {
            S[s] = __builtin_amdgcn_mfma_f32_16x16x32_bf16(aq0, kf[s * 2], z, 0, 0, 0);
            S[s] = __builtin_amdgcn_mfma_f32_16x16x32_bf16(aq1, kf[s * 2 + 1], S[s], 0, 0, 0);
        }

        const bool diag = (t == ntiles - 1);
        #pragma unroll
        for (int s = 0; s < 2; ++s) {
            #pragma unroll
            for (int r = 0; r < 4; ++r) {
                float sv = S[s][r];
                if (diag && (t * 32 + s * 16 + ln > q0 + quad * 4 + r)) sv = -1e30f;
                const unsigned int pu = __float_as_uint(exp2f(sv));
                lp[r] += __uint_as_float(pu & 0xffff0000u);
                pP[(quad * 4 + r) * 40 + s * 16 + ln] = (unsigned short)(pu >> 16);
            }
        }
        __asm__ volatile("s_waitcnt lgkmcnt(0)" ::: "memory");
        const short8 pa = *reinterpret_cast<const short8*>(pP + ln * 40 + quad * 8);
        #pragma unroll
        for (int c = 0; c < 4; ++c)
            O[c] = __builtin_amdgcn_mfma_f32_16x16x32_bf16(pa, vf[c], O[c], 0, 0, 0);
        #pragma unroll
        for (int u = 0; u < 4; ++u) kf[u] = kn[u];
    }

    #pragma unroll
    for (int c = 0; c < 4; ++c)
        #pragma unroll
        for (int r = 0; r < 4; ++r)
            o_lds[w][quad * 4 + r][c * 16 + ln] = O[c][r];
    #pragma unroll
    for (int r = 0; r < 4; ++r) {
        const float ls = rsum16(lp[r]);
        if (ln == 0) l_lds[w][quad * 4 + r] = ls;
    }
    __syncthreads();

    const int qq = threadIdx.x >> 4;
    const int dg = threadIdx.x & 15;
    const float ltot = l_lds[0][qq] + l_lds[1][qq] + l_lds[2][qq] + l_lds[3][qq];
    const float inv = 1.0f / ltot;
    const float4 a0 = *reinterpret_cast<float4*>(&o_lds[0][qq][dg * 4]);
    const float4 a1 = *reinterpret_cast<float4*>(&o_lds[1][qq][dg * 4]);
    const float4 a2 = *reinterpret_cast<float4*>(&o_lds[2][qq][dg * 4]);
    const float4 a3 = *reinterpret_cast<float4*>(&o_lds[3][qq][dg * 4]);
    float4 r;
    r.x = (a0.x + a1.x + a2.x + a3.x) * inv;
    r.y = (a0.y + a1.y + a2.y + a3.y) * inv;
    r.z = (a0.z + a1.z + a2.z + a3.z) * inv;
    r.w = (a0.w + a1.w + a2.w + a3.w) * inv;
    *reinterpret_cast<float4*>(out + ((size_t)b * Tn + q0 + qq) * Hn + dg * 4) = r;
}

// ---------------------------------------------------------------------------
extern "C" void kernel_launch(void* const* d_in, const int* in_sizes, int n_in,
                              void* d_out, int out_size, void* d_ws, size_t ws_size,
                              hipStream_t stream) {
    (void)in_sizes; (void)n_in; (void)out_size; (void)ws_size;
    const float* x  = (const float*)d_in[0];
    const float* Wq = (const float*)d_in[1];
    const float* Wk = (const float*)d_in[2];
    const float* Wv = (const float*)d_in[3];
    float* out = (float*)d_out;

    unsigned short* Wfrag = (unsigned short*)d_ws;            // 196608
    unsigned short* qbf   = Wfrag + (size_t)196608;           // 1048576
    unsigned short* kfr   = qbf + (size_t)Bn * Tn * Hn;       // 1048576
    unsigned short* vfr   = kfr + (size_t)Bn * 131072;        // 1048576

    prep_w<<<96, 256, 0, stream>>>(Wq, Wk, Wv, Wfrag);
    proj_mfma<<<(Bn * Tn) / 16, 256, 0, stream>>>(x, Wfrag, qbf, kfr, vfr);
    attn_mfma<<<Bn * (Tn / 16), 256, 0, stream>>>(qbf, kfr, vfr, out);
}